// Round 1
// baseline (118.219 us; speedup 1.0000x reference)
//
#include <hip/hip_runtime.h>

// AgreementRouting (capsule dynamic routing), MI355X / gfx950.
// B=128, IC=1152, OC=10, D=16, 3 routing iterations, all f32.
//
// Layout: u[((b*IC+i)*OC+j)*D+d], b_in[i*OC+j], out v[(b*OC+j)*D+d].
// ws: s (B*OC*D) | v (B*OC*D) | bb_state (B*IC*OC)  ~= 5.8 MB.

#define BB   128
#define IC   1152
#define OC   10
#define DD   16
#define ICHUNK 16                 // i-rows per block (16 groups of 16 lanes)
#define NBLK_I (IC / ICHUNK)      // 72
#define SOUT (BB * OC * DD)       // 20480

// MODE 0: bb = b_in, no dot, no bb write        (initial c = softmax(b))
// MODE 1: bb = b_in + dot(u,v), write bb_state  (iteration 1)
// MODE 2: bb = bb_state + dot(u,v), write       (iteration 2)
// MODE 3: bb = bb_state + dot(u,v), no write    (iteration 3, last)
template<int MODE>
__global__ __launch_bounds__(256) void acc_kernel(
    const float* __restrict__ u, const float* __restrict__ b_in,
    const float* __restrict__ v, float* __restrict__ bb_state,
    float* __restrict__ s)
{
    const int blk  = blockIdx.x;
    const int b    = blk / NBLK_I;
    const int ich  = blk % NBLK_I;
    const int tid  = threadIdx.x;
    const int grp  = tid >> 4;      // 0..15 (i within chunk)
    const int d    = tid & 15;      // dim lane
    const int i    = ich * ICHUNK + grp;

    const float* urow = u + (size_t)(b * IC + i) * (OC * DD);

    // load this lane's u column (d fixed, j=0..9): 64B contiguous per group
    float uj[OC];
#pragma unroll
    for (int j = 0; j < OC; ++j) uj[j] = urow[j * DD + d];

    // routing logits
    float bb[OC];
    if (MODE == 0 || MODE == 1) {
#pragma unroll
        for (int j = 0; j < OC; ++j) bb[j] = b_in[i * OC + j];
    } else {
        const float* bbp = bb_state + (size_t)(b * IC + i) * OC;
#pragma unroll
        for (int j = 0; j < OC; ++j) bb[j] = bbp[j];
    }

    if (MODE >= 1) {
        const float* vrow = v + (size_t)b * OC * DD;
#pragma unroll
        for (int j = 0; j < OC; ++j) {
            float p = uj[j] * vrow[j * DD + d];
            // sum over d within the 16-lane group (replicated result)
            p += __shfl_xor(p, 1, 16);
            p += __shfl_xor(p, 2, 16);
            p += __shfl_xor(p, 4, 16);
            p += __shfl_xor(p, 8, 16);
            bb[j] += p;
        }
        if (MODE == 1 || MODE == 2) {
            float* bbp = bb_state + (size_t)(b * IC + i) * OC;
            if (d == 0) {
#pragma unroll
                for (int j = 0; j < OC; ++j) bbp[j] = bb[j];
            }
        }
    }

    // softmax over j (replicated across the 16 lanes)
    float m = bb[0];
#pragma unroll
    for (int j = 1; j < OC; ++j) m = fmaxf(m, bb[j]);
    float c[OC];
    float sum = 0.0f;
#pragma unroll
    for (int j = 0; j < OC; ++j) { c[j] = __expf(bb[j] - m); sum += c[j]; }
    const float inv = 1.0f / sum;

    // s contribution for this lane's d: sc[j] = c[j]*u[j][d]
    float sc[OC];
#pragma unroll
    for (int j = 0; j < OC; ++j) sc[j] = c[j] * inv * uj[j];

    // reduce across the 4 groups of this wave (lane bits 4,5)
#pragma unroll
    for (int j = 0; j < OC; ++j) {
        sc[j] += __shfl_xor(sc[j], 16, 64);
        sc[j] += __shfl_xor(sc[j], 32, 64);
    }

    // cross-wave reduce via LDS, then one atomic per (j,d) per block
    __shared__ float red[4][OC * DD];
    const int wave = tid >> 6;
    const int lane = tid & 63;
    if (lane < DD) {
#pragma unroll
        for (int j = 0; j < OC; ++j) red[wave][j * DD + lane] = sc[j];
    }
    __syncthreads();
    if (tid < OC * DD) {
        float t = red[0][tid] + red[1][tid] + red[2][tid] + red[3][tid];
        atomicAdd(&s[(size_t)b * OC * DD + tid], t);
    }
}

// squash s -> vout; optionally zero s for the next accumulation pass
template<bool ZERO_S>
__global__ __launch_bounds__(256) void squash_kernel(
    float* __restrict__ s, float* __restrict__ vout)
{
    const int idx = blockIdx.x * 256 + threadIdx.x;   // 0..SOUT-1
    float x = s[idx];
    float sq = x * x;
    sq += __shfl_xor(sq, 1, 16);
    sq += __shfl_xor(sq, 2, 16);
    sq += __shfl_xor(sq, 4, 16);
    sq += __shfl_xor(sq, 8, 16);
    const float scale = sq / (1.0f + sq);
    vout[idx] = scale * x * rsqrtf(sq + 1e-8f);
    if (ZERO_S) s[idx] = 0.0f;
}

__global__ __launch_bounds__(256) void zero_kernel(float* __restrict__ s)
{
    s[blockIdx.x * 256 + threadIdx.x] = 0.0f;
}

extern "C" void kernel_launch(void* const* d_in, const int* in_sizes, int n_in,
                              void* d_out, int out_size, void* d_ws, size_t ws_size,
                              hipStream_t stream) {
    const float* u    = (const float*)d_in[0];
    const float* b_in = (const float*)d_in[1];
    float* out = (float*)d_out;

    float* s  = (float*)d_ws;        // SOUT floats
    float* v  = s + SOUT;            // SOUT floats
    float* bb = v + SOUT;            // B*IC*OC floats

    const dim3 accGrid(BB * NBLK_I);
    const dim3 blk(256);
    const dim3 sGrid(SOUT / 256);

    zero_kernel<<<sGrid, blk, 0, stream>>>(s);

    // initial: c = softmax(b); s = sum_i c*u; v = squash(s)
    acc_kernel<0><<<accGrid, blk, 0, stream>>>(u, b_in, nullptr, nullptr, s);
    squash_kernel<true><<<sGrid, blk, 0, stream>>>(s, v);

    // iteration 1
    acc_kernel<1><<<accGrid, blk, 0, stream>>>(u, b_in, v, bb, s);
    squash_kernel<true><<<sGrid, blk, 0, stream>>>(s, v);

    // iteration 2
    acc_kernel<2><<<accGrid, blk, 0, stream>>>(u, b_in, v, bb, s);
    squash_kernel<true><<<sGrid, blk, 0, stream>>>(s, v);

    // iteration 3 (final; write d_out)
    acc_kernel<3><<<accGrid, blk, 0, stream>>>(u, b_in, v, bb, s);
    squash_kernel<false><<<sGrid, blk, 0, stream>>>(s, out);
}

// Round 2
// 107.619 us; speedup vs baseline: 1.0985x; 1.0985x over previous
//
#include <hip/hip_runtime.h>
#include <hip/hip_bf16.h>

// AgreementRouting (capsule dynamic routing), MI355X / gfx950.
// B=128, IC=1152, OC=10, D=16, 3 iterations, f32 in/out.
//
// Structure (6 launches):
//   Z  : zero s0..s3 (4 x 20480 f32)
//   A0 : read f32 u -> accumulate s0 (c=softmax(b_in)); write bf16 copy of u
//   A<T=1,2,3>: inline-squash s0..s_{T-1} -> vsum in LDS; bb = b_in + <u,vsum>
//               (linearity: sum of per-iteration dots == dot with summed v);
//               c=softmax(bb); accumulate s_T.  u read as bf16 (47.2 MB).
//   F  : squash s3 -> out
//
// Lane scheme per 16-lane group (one (b,i) slice = 10x16 floats):
//   l = tid&15, h = l>>3 (j parity), p = l&7 (d-pair). Lane owns elements
//   (j=2k+h, d=2p..2p+1), k=0..4  == linear float offset 32k+2l (contiguous).

#define B_    128
#define IC_   1152
#define OC_   10
#define ROW_  160          // OC_*16
#define WPS_  80           // bf16 dwords per slice
#define ICH_  16           // slices per block
#define NBI_  72           // IC_/ICH_
#define SOUT_ 20480        // B_*ROW_

__device__ __forceinline__ float bf_lo(uint32_t w) { return __uint_as_float(w << 16); }
__device__ __forceinline__ float bf_hi(uint32_t w) { return __uint_as_float(w & 0xffff0000u); }

__global__ __launch_bounds__(256) void z_kernel(float* __restrict__ s) {
    s[blockIdx.x * 256 + threadIdx.x] = 0.0f;
}

// ---- stage 0: f32 u -> s0, plus bf16(u) copy ----
__global__ __launch_bounds__(256) void a0_kernel(
    const float* __restrict__ u, const float* __restrict__ b_in,
    float* __restrict__ s0, uint32_t* __restrict__ u16)
{
    const int blk = blockIdx.x, b = blk / NBI_, ich = blk % NBI_;
    const int tid = threadIdx.x;
    const int l = tid & 15, h = l >> 3;
    const int i = ich * ICH_ + (tid >> 4);

    const float* up = u + (size_t)(b * IC_ + i) * ROW_;
    float2 uv[5];
#pragma unroll
    for (int k = 0; k < 5; ++k)
        uv[k] = *(const float2*)(up + 32 * k + 2 * l);   // 128B contiguous/group

    // write bf16 copy (RNE), linear (j,d) order -> 64B contiguous/group
    uint32_t* wp = u16 + (size_t)(b * IC_ + i) * WPS_;
#pragma unroll
    for (int k = 0; k < 5; ++k) {
        __hip_bfloat16 bx = __float2bfloat16(uv[k].x);
        __hip_bfloat16 by = __float2bfloat16(uv[k].y);
        uint32_t w = ((uint32_t)(*(const uint16_t*)&by) << 16) |
                      (uint32_t)(*(const uint16_t*)&bx);
        wp[16 * k + l] = w;
    }

    // logits = b_in row (j = 2k+h)
    float own[5], oth[5];
#pragma unroll
    for (int k = 0; k < 5; ++k) own[k] = b_in[i * OC_ + 2 * k + h];
    float m = -1e30f;
#pragma unroll
    for (int k = 0; k < 5; ++k) {
        oth[k] = __shfl_xor(own[k], 8, 16);
        m = fmaxf(m, fmaxf(own[k], oth[k]));
    }
    float sum = 0.f;
#pragma unroll
    for (int k = 0; k < 5; ++k) {
        own[k] = __expf(own[k] - m);
        sum += own[k] + __expf(oth[k] - m);
    }
    const float inv = 1.f / sum;

    float2 sc[5];
#pragma unroll
    for (int k = 0; k < 5; ++k) {
        float c = own[k] * inv;
        sc[k].x = c * uv[k].x; sc[k].y = c * uv[k].y;
    }
    // reduce across the 4 groups of this wave
#pragma unroll
    for (int k = 0; k < 5; ++k) {
        sc[k].x += __shfl_xor(sc[k].x, 16); sc[k].y += __shfl_xor(sc[k].y, 16);
        sc[k].x += __shfl_xor(sc[k].x, 32); sc[k].y += __shfl_xor(sc[k].y, 32);
    }
    __shared__ float red[4][ROW_];
    const int wave = tid >> 6, lane = tid & 63;
    if (lane < 16) {
#pragma unroll
        for (int k = 0; k < 5; ++k)
            *(float2*)&red[wave][32 * k + 2 * l] = sc[k];
    }
    __syncthreads();
    if (tid < ROW_) {
        float t = red[0][tid] + red[1][tid] + red[2][tid] + red[3][tid];
        atomicAdd(&s0[b * ROW_ + tid], t);
    }
}

// ---- stages 1..3: bf16 u; vsum = sum of squash(s_t), t<T; one dot ----
template<int T>
__global__ __launch_bounds__(256) void ai_kernel(
    const uint32_t* __restrict__ u16, const float* __restrict__ b_in,
    const float* __restrict__ s_all, float* __restrict__ s_next)
{
    const int blk = blockIdx.x, b = blk / NBI_, ich = blk % NBI_;
    const int tid = threadIdx.x;
    const int l = tid & 15, h = l >> 3;
    const int i = ich * ICH_ + (tid >> 4);

    __shared__ float v_lds[ROW_];
    if (tid < ROW_) {
        float vsum = 0.f;
#pragma unroll
        for (int t = 0; t < T; ++t) {
            float x = s_all[t * SOUT_ + b * ROW_ + tid];
            float sq = x * x;
            sq += __shfl_xor(sq, 1, 16);
            sq += __shfl_xor(sq, 2, 16);
            sq += __shfl_xor(sq, 4, 16);
            sq += __shfl_xor(sq, 8, 16);
            vsum += (sq / (1.f + sq)) * x * rsqrtf(sq + 1e-8f);
        }
        v_lds[tid] = vsum;
    }
    __syncthreads();

    const uint32_t* wp = u16 + (size_t)(b * IC_ + i) * WPS_;
    uint32_t uw[5];
#pragma unroll
    for (int k = 0; k < 5; ++k) uw[k] = wp[16 * k + l];

    // bb = b_in + <u, vsum> over d (reduce over 8 d-pair lanes)
    float own[5], oth[5];
#pragma unroll
    for (int k = 0; k < 5; ++k) {
        float2 vv = *(const float2*)&v_lds[32 * k + 2 * l];
        float pd = bf_lo(uw[k]) * vv.x + bf_hi(uw[k]) * vv.y;
        pd += __shfl_xor(pd, 1, 16);
        pd += __shfl_xor(pd, 2, 16);
        pd += __shfl_xor(pd, 4, 16);
        own[k] = b_in[i * OC_ + 2 * k + h] + pd;
    }
    float m = -1e30f;
#pragma unroll
    for (int k = 0; k < 5; ++k) {
        oth[k] = __shfl_xor(own[k], 8, 16);
        m = fmaxf(m, fmaxf(own[k], oth[k]));
    }
    float sum = 0.f;
#pragma unroll
    for (int k = 0; k < 5; ++k) {
        own[k] = __expf(own[k] - m);
        sum += own[k] + __expf(oth[k] - m);
    }
    const float inv = 1.f / sum;

    float2 sc[5];
#pragma unroll
    for (int k = 0; k < 5; ++k) {
        float c = own[k] * inv;
        sc[k].x = c * bf_lo(uw[k]); sc[k].y = c * bf_hi(uw[k]);
    }
#pragma unroll
    for (int k = 0; k < 5; ++k) {
        sc[k].x += __shfl_xor(sc[k].x, 16); sc[k].y += __shfl_xor(sc[k].y, 16);
        sc[k].x += __shfl_xor(sc[k].x, 32); sc[k].y += __shfl_xor(sc[k].y, 32);
    }
    __shared__ float red[4][ROW_];
    const int wave = tid >> 6, lane = tid & 63;
    if (lane < 16) {
#pragma unroll
        for (int k = 0; k < 5; ++k)
            *(float2*)&red[wave][32 * k + 2 * l] = sc[k];
    }
    __syncthreads();
    if (tid < ROW_) {
        float t = red[0][tid] + red[1][tid] + red[2][tid] + red[3][tid];
        atomicAdd(&s_next[b * ROW_ + tid], t);
    }
}

// ---- final squash: s3 -> out ----
__global__ __launch_bounds__(256) void f_kernel(
    const float* __restrict__ s, float* __restrict__ out)
{
    const int idx = blockIdx.x * 256 + threadIdx.x;
    float x = s[idx];
    float sq = x * x;
    sq += __shfl_xor(sq, 1, 16);
    sq += __shfl_xor(sq, 2, 16);
    sq += __shfl_xor(sq, 4, 16);
    sq += __shfl_xor(sq, 8, 16);
    out[idx] = (sq / (1.f + sq)) * x * rsqrtf(sq + 1e-8f);
}

extern "C" void kernel_launch(void* const* d_in, const int* in_sizes, int n_in,
                              void* d_out, int out_size, void* d_ws, size_t ws_size,
                              hipStream_t stream) {
    const float* u    = (const float*)d_in[0];
    const float* b_in = (const float*)d_in[1];
    float* out = (float*)d_out;

    float*    s_all = (float*)d_ws;                 // 4 * SOUT_ floats
    uint32_t* u16   = (uint32_t*)(s_all + 4 * SOUT_); // 11.8M dwords (47.2 MB)

    const dim3 blk(256);
    const dim3 accGrid(B_ * NBI_);      // 9216

    z_kernel<<<4 * SOUT_ / 256, blk, 0, stream>>>(s_all);
    a0_kernel<<<accGrid, blk, 0, stream>>>(u, b_in, s_all, u16);
    ai_kernel<1><<<accGrid, blk, 0, stream>>>(u16, b_in, s_all, s_all + 1 * SOUT_);
    ai_kernel<2><<<accGrid, blk, 0, stream>>>(u16, b_in, s_all, s_all + 2 * SOUT_);
    ai_kernel<3><<<accGrid, blk, 0, stream>>>(u16, b_in, s_all, s_all + 3 * SOUT_);
    f_kernel<<<SOUT_ / 256, blk, 0, stream>>>(s_all + 3 * SOUT_, out);
}